// Round 2
// baseline (30564.111 us; speedup 1.0000x reference)
//
#include <hip/hip_runtime.h>

#define BB 512
#define LL 2000
#define DD 16
#define HH 128
#define WD 256
#define NLBL 10
#define NSTEPS 500
#define G 16
#define NWG (BB / G)
#define NTHR 1024

typedef __bf16 bf16x8 __attribute__((ext_vector_type(8)));
typedef float f32x4 __attribute__((ext_vector_type(4)));

__device__ __forceinline__ unsigned short f2bf(float f) {
  unsigned int u = __float_as_uint(f);
  u += 0x7FFFu + ((u >> 16) & 1u);
  return (unsigned short)(u >> 16);
}

// XOR-swizzled element offset into a [G][WD] bf16 LDS tile (8-elem chunks)
__device__ __forceinline__ int swz(int r, int c) {
  return r * WD + ((((c >> 3) ^ (r & 7)) << 3) | (c & 7));
}

__device__ __forceinline__ bf16x8 ldfrag(const unsigned short* buf, int row, int chunk) {
  return *reinterpret_cast<const bf16x8*>(buf + row * WD + ((chunk ^ (row & 7)) << 3));
}

struct __align__(16) SM {
  float Y[G][HH];
  float K1[G][HH];
  float F[G][HH];
  unsigned short X[G * WD];   // swizzled bf16 activations (input / H2)
  unsigned short Hb[G * WD];  // swizzled bf16 H1
  float dx[2][G][DD];
  float b1[WD], b2[WD];
  float b3[HH * DD];
  float tau_tab[2 * NSTEPS];
  unsigned short idx_tab[2 * NSTEPS];
  float logits[G * NLBL];
};

__global__ void prep(const float* __restrict__ W1, const float* __restrict__ W2,
                     const float* __restrict__ W3,
                     unsigned short* __restrict__ w1b, unsigned short* __restrict__ w2b,
                     unsigned short* __restrict__ w3b) {
  int i = blockIdx.x * blockDim.x + threadIdx.x;
  if (i < HH * DD * WD) w3b[i] = f2bf(W3[i]);
  if (i < WD * WD) w2b[i] = f2bf(W2[i]);
  if (i < WD * HH) w1b[i] = f2bf(W1[i]);
}

__global__ __launch_bounds__(NTHR) void cde_main(
    const float* __restrict__ ts, const float* __restrict__ coeffs,
    const float* __restrict__ x0,
    const float* __restrict__ b1g, const float* __restrict__ b2g, const float* __restrict__ b3g,
    const float* __restrict__ Wl1, const float* __restrict__ bl1,
    const float* __restrict__ Wl2, const float* __restrict__ bl2,
    const unsigned short* __restrict__ w1b, const unsigned short* __restrict__ w2b,
    const unsigned short* __restrict__ w3b,
    float* __restrict__ out) {
  __shared__ SM sm;
  const int tid = threadIdx.x;
  const int gb = blockIdx.x * G;
  const int w = tid >> 6, lane = tid & 63;
  const int row16 = lane & 15, kg = lane >> 4;

  const float ts0 = ts[0];
  const float dt = (ts[LL - 1] - ts0) / (float)NSTEPS;

  for (int i = tid; i < WD; i += NTHR) { sm.b1[i] = b1g[i]; sm.b2[i] = b2g[i]; }
  for (int i = tid; i < HH * DD; i += NTHR) sm.b3[i] = b3g[i];

  // idx/tau table, bit-faithful to reference time arithmetic
  for (int e = tid; e < 2 * NSTEPS; e += NTHR) {
    int kk = e >> 1;
    float t = ts0 + (float)kk * dt;
    if (e & 1) t = t + dt;
    int lo = 0, hi = LL;
    while (lo < hi) { int m = (lo + hi) >> 1; if (ts[m] <= t) lo = m + 1; else hi = m; }
    int idx = lo - 1;
    if (idx < 0) idx = 0;
    if (idx > LL - 2) idx = LL - 2;
    sm.idx_tab[e] = (unsigned short)idx;
    sm.tau_tab[e] = t - ts[idx];
  }

  // y0 = x0 @ Wl1^T + bl1
  for (int i = tid; i < G * HH; i += NTHR) {
    int r = i >> 7, h = i & (HH - 1);
    float s = bl1[h];
    const float* xr = x0 + (size_t)(gb + r) * DD;
    const float* wr = Wl1 + (size_t)h * DD;
#pragma unroll
    for (int d = 0; d < DD; ++d) s += xr[d] * wr[d];
    sm.Y[r][h] = s;
  }

  // persistent W1/W2 B-fragments: each wave owns N-tile n = w*16 + row16
  bf16x8 w1f[4], w2f[8];
  const uint4* w1p = reinterpret_cast<const uint4*>(w1b);
  const uint4* w2p = reinterpret_cast<const uint4*>(w2b);
  const uint4* w3p = reinterpret_cast<const uint4*>(w3b);
  {
    int n = w * 16 + row16;
#pragma unroll
    for (int s = 0; s < 4; ++s) w1f[s] = __builtin_bit_cast(bf16x8, w1p[n * 16 + s * 4 + kg]);
#pragma unroll
    for (int s = 0; s < 8; ++s) w2f[s] = __builtin_bit_cast(bf16x8, w2p[n * 32 + s * 4 + kg]);
  }
  __syncthreads();

  // b3 values for this wave's 8 phase-D tiles, hoisted into registers
  float b3v[8];
#pragma unroll
  for (int j = 0; j < 8; ++j) b3v[j] = sm.b3[(w + j * 16) * 16 + row16];

  auto ldw3 = [&](int nrow, int f) -> bf16x8 {
    return __builtin_bit_cast(bf16x8, w3p[nrow * 32 + f * 4 + kg]);
  };

  for (int k = 0; k < NSTEPS; ++k) {
    for (int mode = 0; mode < 2; ++mode) {
      float(*dest)[HH] = mode ? sm.F : sm.K1;

      // ---- phase A: stage input activations (bf16, swizzled) + dX prefetch
      for (int i = tid; i < G * HH; i += NTHR) {
        int r = i >> 7, c = i & (HH - 1);
        float v = sm.Y[r][c];
        if (mode) v += dt * sm.K1[r][c];
        sm.X[swz(r, c)] = f2bf(v);
      }
      if (mode == 0 && tid < 512) {  // compute dX for BOTH Heun stages now
        int which = tid >> 8, j = tid & 255;
        int r = j >> 4, d = j & 15;
        int e = 2 * k + which;
        int idx = sm.idx_tab[e];
        float tau = sm.tau_tab[e];
        const float* cb = coeffs + ((size_t)(gb + r) * 4 * (LL - 1) + idx) * DD + d;
        float c0 = __builtin_nontemporal_load(cb);                          // d_
        float c1 = __builtin_nontemporal_load(cb + (size_t)(LL - 1) * DD);  // c_
        float c2 = __builtin_nontemporal_load(cb + (size_t)2 * (LL - 1) * DD); // b_
        sm.dx[which][r][d] = c2 + 2.0f * tau * c1 + 3.0f * tau * tau * c0;
      }
      __syncthreads();

      // ---- phase B: H1 = relu(X @ W1^T + b1)   (M=16,N=256,K=128)
      {
        f32x4 acc = {0.f, 0.f, 0.f, 0.f};
#pragma unroll
        for (int s = 0; s < 4; ++s) {
          bf16x8 a = ldfrag(sm.X, row16, s * 4 + kg);
          acc = __builtin_amdgcn_mfma_f32_16x16x32_bf16(a, w1f[s], acc, 0, 0, 0);
        }
        int n = w * 16 + row16;
#pragma unroll
        for (int v = 0; v < 4; ++v) {
          int r = kg * 4 + v;
          float o = acc[v] + sm.b1[n];
          sm.Hb[swz(r, n)] = f2bf(fmaxf(o, 0.f));
        }
      }
      __syncthreads();

      // ---- phase C: H2 = relu(H1 @ W2^T + b2)  (M=16,N=256,K=256) -> X
      {
        f32x4 acc = {0.f, 0.f, 0.f, 0.f};
#pragma unroll
        for (int s = 0; s < 8; ++s) {
          bf16x8 a = ldfrag(sm.Hb, row16, s * 4 + kg);
          acc = __builtin_amdgcn_mfma_f32_16x16x32_bf16(a, w2f[s], acc, 0, 0, 0);
        }
        int n = w * 16 + row16;
#pragma unroll
        for (int v = 0; v < 4; ++v) {
          int r = kg * 4 + v;
          float o = acc[v] + sm.b2[n];
          sm.X[swz(r, n)] = f2bf(fmaxf(o, 0.f));
        }
      }
      __syncthreads();

      // ---- phase D: O = tanh(H2 @ W3^T + b3); F = sum_d O*dX
      // 8 j-tiles per wave, software-pipelined W3 loads (half-fragment chunks)
      {
        bf16x8 cur[4];
        {
          int nrow0 = w * 16 + row16;
#pragma unroll
          for (int s = 0; s < 4; ++s) cur[s] = ldw3(nrow0, s);
        }
#pragma unroll
        for (int j = 0; j < 8; ++j) {
          const int nt = w + j * 16;       // h index
          const int nrow = nt * 16 + row16;
          f32x4 acc = {0.f, 0.f, 0.f, 0.f};
          bf16x8 nxt[4];
#pragma unroll
          for (int s = 0; s < 4; ++s) nxt[s] = ldw3(nrow, 4 + s);  // issue half-1 loads
#pragma unroll
          for (int s = 0; s < 4; ++s) {
            bf16x8 a = ldfrag(sm.X, row16, s * 4 + kg);
            acc = __builtin_amdgcn_mfma_f32_16x16x32_bf16(a, cur[s], acc, 0, 0, 0);
          }
          if (j < 7) {
            const int nrown = (w + (j + 1) * 16) * 16 + row16;
#pragma unroll
            for (int s = 0; s < 4; ++s) cur[s] = ldw3(nrown, s);   // issue next half-0
          }
#pragma unroll
          for (int s = 0; s < 4; ++s) {
            bf16x8 a = ldfrag(sm.X, row16, (4 + s) * 4 + kg);
            acc = __builtin_amdgcn_mfma_f32_16x16x32_bf16(a, nxt[s], acc, 0, 0, 0);
          }
          float p[4];
#pragma unroll
          for (int v = 0; v < 4; ++v) {
            int r = kg * 4 + v;
            float o = acc[v] + b3v[j];
            float e2 = __expf(2.0f * o);
            float T = 1.0f - 2.0f / (e2 + 1.0f);
            p[v] = T * sm.dx[mode][r][row16];
          }
#pragma unroll
          for (int m = 1; m < 16; m <<= 1) {
#pragma unroll
            for (int v = 0; v < 4; ++v) p[v] += __shfl_xor(p[v], m);
          }
          if (row16 == 0) {
#pragma unroll
            for (int v = 0; v < 4; ++v) dest[kg * 4 + v][nt] = p[v];
          }
        }
      }
      __syncthreads();
    }

    // ---- Heun update
    for (int i = tid; i < G * HH; i += NTHR) {
      int r = i >> 7, c = i & (HH - 1);
      sm.Y[r][c] += 0.5f * dt * (sm.K1[r][c] + sm.F[r][c]);
    }
    __syncthreads();
  }

  // ---- classifier + softmax
  if (tid < G * NLBL) {
    int r = tid / NLBL, c = tid % NLBL;
    float s = bl2[c];
    const float* wr = Wl2 + (size_t)c * HH;
#pragma unroll 4
    for (int h = 0; h < HH; ++h) s += sm.Y[r][h] * wr[h];
    sm.logits[tid] = s;
  }
  __syncthreads();
  if (tid < G) {
    float mx = -1e30f;
#pragma unroll
    for (int c = 0; c < NLBL; ++c) mx = fmaxf(mx, sm.logits[tid * NLBL + c]);
    float e[NLBL], sum = 0.f;
#pragma unroll
    for (int c = 0; c < NLBL; ++c) { e[c] = expf(sm.logits[tid * NLBL + c] - mx); sum += e[c]; }
    float inv = 1.0f / sum;
#pragma unroll
    for (int c = 0; c < NLBL; ++c) out[(size_t)(gb + tid) * NLBL + c] = e[c] * inv;
  }
}

extern "C" void kernel_launch(void* const* d_in, const int* in_sizes, int n_in,
                              void* d_out, int out_size, void* d_ws, size_t ws_size,
                              hipStream_t stream) {
  (void)in_sizes; (void)n_in; (void)out_size; (void)ws_size;
  const float* ts = (const float*)d_in[0];
  const float* coeffs = (const float*)d_in[1];
  const float* x0 = (const float*)d_in[2];
  const float* W1 = (const float*)d_in[3];
  const float* b1 = (const float*)d_in[4];
  const float* W2 = (const float*)d_in[5];
  const float* b2 = (const float*)d_in[6];
  const float* W3 = (const float*)d_in[7];
  const float* b3 = (const float*)d_in[8];
  const float* Wl1 = (const float*)d_in[9];
  const float* bl1 = (const float*)d_in[10];
  const float* Wl2 = (const float*)d_in[11];
  const float* bl2 = (const float*)d_in[12];

  unsigned short* w3b = (unsigned short*)d_ws;                 // 524288 bf16
  unsigned short* w2b = w3b + (HH * DD * WD);                  // 65536 bf16
  unsigned short* w1b = w2b + (WD * WD);                       // 32768 bf16

  prep<<<2048, 256, 0, stream>>>(W1, W2, W3, w1b, w2b, w3b);
  cde_main<<<NWG, NTHR, 0, stream>>>(ts, coeffs, x0, b1, b2, b3, Wl1, bl1, Wl2, bl2,
                                     w1b, w2b, w3b, (float*)d_out);
}

// Round 3
// 30465.677 us; speedup vs baseline: 1.0032x; 1.0032x over previous
//
#include <hip/hip_runtime.h>

#define BB 512
#define LL 2000
#define DD 16
#define HH 128
#define WD 256
#define NLBL 10
#define NSTEPS 500
#define G 16
#define NWG (BB / G)
#define NTHR 1024

typedef __bf16 bf16x8 __attribute__((ext_vector_type(8)));
typedef float f32x4 __attribute__((ext_vector_type(4)));

__device__ __forceinline__ unsigned short f2bf(float f) {
  unsigned int u = __float_as_uint(f);
  u += 0x7FFFu + ((u >> 16) & 1u);
  return (unsigned short)(u >> 16);
}

// XOR-swizzled element offset into a [rows][256] bf16 LDS tile (16B chunks)
__device__ __forceinline__ int swz(int r, int c) {
  return r * WD + ((((c >> 3) ^ (r & 7)) << 3) | (c & 7));
}

__device__ __forceinline__ bf16x8 ldfrag(const unsigned short* buf, int row, int chunk) {
  return *reinterpret_cast<const bf16x8*>(buf + row * WD + ((chunk ^ (row & 7)) << 3));
}

struct __align__(16) SM {
  float Y[G][HH];
  float K1[G][HH];
  float F[G][HH];
  unsigned short X[G * WD];    // swizzled bf16 activations (input / H2)
  unsigned short Hb[G * WD];   // swizzled bf16 H1
  float dx[2][2][G][DD];       // [step&1][stage][row][d]
  float b1[WD], b2[WD];
  float b3[HH * DD];
  float tsl[LL];
  float tau_tab[2 * NSTEPS];
  unsigned short idx_tab[2 * NSTEPS];
  float logits[G * NLBL];
  unsigned short w1[WD * HH];  // swizzled bf16 W1 (B-fragments), 64KB
};

__global__ void prep(const float* __restrict__ W1, const float* __restrict__ W2,
                     const float* __restrict__ W3,
                     unsigned short* __restrict__ w1b, unsigned short* __restrict__ w2b,
                     unsigned short* __restrict__ w3b) {
  int i = blockIdx.x * blockDim.x + threadIdx.x;
  if (i < HH * DD * WD) w3b[i] = f2bf(W3[i]);
  if (i < WD * WD) w2b[i] = f2bf(W2[i]);
  if (i < WD * HH) w1b[i] = f2bf(W1[i]);
}

__global__ __launch_bounds__(NTHR) void cde_main(
    const float* __restrict__ ts, const float* __restrict__ coeffs,
    const float* __restrict__ x0,
    const float* __restrict__ b1g, const float* __restrict__ b2g, const float* __restrict__ b3g,
    const float* __restrict__ Wl1, const float* __restrict__ bl1,
    const float* __restrict__ Wl2, const float* __restrict__ bl2,
    const unsigned short* __restrict__ w1b, const unsigned short* __restrict__ w2b,
    const unsigned short* __restrict__ w3b,
    float* __restrict__ out) {
  extern __shared__ char smraw[];
  SM& sm = *reinterpret_cast<SM*>(smraw);
  const int tid = threadIdx.x;
  const int gb = blockIdx.x * G;
  const int w = tid >> 6, lane = tid & 63;
  const int row16 = lane & 15, kg = lane >> 4;

  const float ts0 = ts[0];
  const float dt = (ts[LL - 1] - ts0) / (float)NSTEPS;

  // ---- prologue stage 1: LDS fills with no cross-deps
  for (int i = tid; i < LL; i += NTHR) sm.tsl[i] = ts[i];
  for (int i = tid; i < WD; i += NTHR) { sm.b1[i] = b1g[i]; sm.b2[i] = b2g[i]; }
  for (int i = tid; i < HH * DD; i += NTHR) sm.b3[i] = b3g[i];
  // W1 -> LDS, swizzled 16B chunks: row n (256B), chunk kc -> kc^(n&7)
  {
    const uint4* w1p4 = reinterpret_cast<const uint4*>(w1b);
    for (int i = tid; i < WD * HH / 8; i += NTHR) {
      int n = i >> 4, kc = i & 15;
      uint4 v = w1p4[i];
      *reinterpret_cast<uint4*>(&sm.w1[n * HH + (((kc ^ (n & 7)) << 3))]) = v;
    }
  }
  // y0 = x0 @ Wl1^T + bl1
  for (int i = tid; i < G * HH; i += NTHR) {
    int r = i >> 7, h = i & (HH - 1);
    float s = bl1[h];
    const float* xr = x0 + (size_t)(gb + r) * DD;
    const float* wr = Wl1 + (size_t)h * DD;
#pragma unroll
    for (int d = 0; d < DD; ++d) s += xr[d] * wr[d];
    sm.Y[r][h] = s;
  }
  // persistent W2 B-fragments (32 VGPR): wave owns N-tile n = w*16+row16
  bf16x8 w2f[8];
  const uint4* w2p = reinterpret_cast<const uint4*>(w2b);
  const uint4* w3p = reinterpret_cast<const uint4*>(w3b);
  {
    int n = w * 16 + row16;
#pragma unroll
    for (int s = 0; s < 8; ++s) w2f[s] = __builtin_bit_cast(bf16x8, w2p[n * 32 + s * 4 + kg]);
  }
  __syncthreads();

  // ---- prologue stage 2: idx/tau tables (bit-faithful to reference arithmetic)
  for (int e = tid; e < 2 * NSTEPS; e += NTHR) {
    int kk = e >> 1;
    float t = ts0 + (float)kk * dt;
    if (e & 1) t = t + dt;
    int lo = 0, hi = LL;
    while (lo < hi) { int m = (lo + hi) >> 1; if (sm.tsl[m] <= t) lo = m + 1; else hi = m; }
    int idx = lo - 1;
    if (idx < 0) idx = 0;
    if (idx > LL - 2) idx = LL - 2;
    sm.idx_tab[e] = (unsigned short)idx;
    sm.tau_tab[e] = t - sm.tsl[idx];
  }
  __syncthreads();

  // ---- prologue stage 3: dx for step 0 (both stages)
  if (tid >= 512) {
    int q = tid - 512;
    int which = q >> 8, rr = (q >> 4) & 15, d = q & 15;
    int idx = sm.idx_tab[which];
    float tau = sm.tau_tab[which];
    const float* cb = coeffs + ((size_t)(gb + rr) * 4 * (LL - 1) + idx) * DD + d;
    float c0 = cb[0];
    float c1 = cb[(size_t)(LL - 1) * DD];
    float c2 = cb[(size_t)2 * (LL - 1) * DD];
    sm.dx[0][which][rr][d] = c2 + 2.0f * tau * c1 + 3.0f * tau * tau * c0;
  }
  __syncthreads();

  const int nbase = w * 16 + row16;                 // phase-D W3 row base
  const uint4* w3base = w3p + (size_t)nbase * 32 + kg;
#define LDW3(j, f) __builtin_bit_cast(bf16x8, w3base[(size_t)(j) * 8192 + (f) * 4])

  float pc0 = 0.f, pc1 = 0.f, pc2 = 0.f, ptau = 0.f;  // next-step coeff prefetch

  for (int k = 0; k < NSTEPS; ++k) {
    for (int mode = 0; mode < 2; ++mode) {
      float(*dest)[HH] = mode ? sm.F : sm.K1;

      // ---- phase A: stage activations (bf16, swizzled); issue next-step coeff loads
      for (int i = tid; i < G * HH; i += NTHR) {
        int r = i >> 7, c = i & (HH - 1);
        float v = sm.Y[r][c];
        if (mode) v += dt * sm.K1[r][c];
        sm.X[swz(r, c)] = f2bf(v);
      }
      if (mode == 0 && tid >= 512) {
        int q = tid - 512;
        int which = q >> 8, rr = (q >> 4) & 15, d = q & 15;
        int e = 2 * (k + 1) + which;
        if (e > 2 * NSTEPS - 1) e = 2 * NSTEPS - 1;
        int idx = sm.idx_tab[e];
        ptau = sm.tau_tab[e];
        const float* cb = coeffs + ((size_t)(gb + rr) * 4 * (LL - 1) + idx) * DD + d;
        pc0 = cb[0];
        pc1 = cb[(size_t)(LL - 1) * DD];
        pc2 = cb[(size_t)2 * (LL - 1) * DD];
      }
      __syncthreads();

      // ---- phase B: H1 = relu(X @ W1^T + b1)  (W1 frags from LDS)
      {
        const int n = w * 16 + row16;
        f32x4 acc = {0.f, 0.f, 0.f, 0.f};
#pragma unroll
        for (int s = 0; s < 4; ++s) {
          bf16x8 a = ldfrag(sm.X, row16, s * 4 + kg);
          bf16x8 b = *reinterpret_cast<const bf16x8*>(
              &sm.w1[n * HH + ((((s * 4 + kg) ^ (n & 7)) << 3))]);
          acc = __builtin_amdgcn_mfma_f32_16x16x32_bf16(a, b, acc, 0, 0, 0);
        }
#pragma unroll
        for (int v = 0; v < 4; ++v) {
          int r = kg * 4 + v;
          float o = acc[v] + sm.b1[n];
          sm.Hb[swz(r, n)] = f2bf(fmaxf(o, 0.f));
        }
      }
      __syncthreads();

      // ---- phase C: H2 = relu(H1 @ W2^T + b2) -> X
      {
        const int n = w * 16 + row16;
        f32x4 acc = {0.f, 0.f, 0.f, 0.f};
#pragma unroll
        for (int s = 0; s < 8; ++s) {
          bf16x8 a = ldfrag(sm.Hb, row16, s * 4 + kg);
          acc = __builtin_amdgcn_mfma_f32_16x16x32_bf16(a, w2f[s], acc, 0, 0, 0);
        }
#pragma unroll
        for (int v = 0; v < 4; ++v) {
          int r = kg * 4 + v;
          float o = acc[v] + sm.b2[n];
          sm.X[swz(r, n)] = f2bf(fmaxf(o, 0.f));
        }
      }
      __syncthreads();

      // ---- phase D: O = tanh(H2 @ W3^T + b3); F = sum_d O*dX
      {
        // hoist A-fragments (read once instead of per-j)
        bf16x8 aD[8];
#pragma unroll
        for (int s = 0; s < 8; ++s) aD[s] = ldfrag(sm.X, row16, s * 4 + kg);
        float dxr[4];
#pragma unroll
        for (int v = 0; v < 4; ++v) dxr[v] = sm.dx[k & 1][mode][kg * 4 + v][row16];

        // 8-deep W3 pipeline: two 4-frag ring buffers, refill right after use
        bf16x8 r0[4], r1[4];
#pragma unroll
        for (int s = 0; s < 4; ++s) r0[s] = LDW3(0, s);
#pragma unroll
        for (int s = 0; s < 4; ++s) r1[s] = LDW3(0, 4 + s);

#pragma unroll
        for (int j = 0; j < 8; ++j) {
          f32x4 acc = {0.f, 0.f, 0.f, 0.f};
#pragma unroll
          for (int s = 0; s < 4; ++s)
            acc = __builtin_amdgcn_mfma_f32_16x16x32_bf16(aD[s], r0[s], acc, 0, 0, 0);
          if (j < 7) {
#pragma unroll
            for (int s = 0; s < 4; ++s) r0[s] = LDW3(j + 1, s);
          }
#pragma unroll
          for (int s = 0; s < 4; ++s)
            acc = __builtin_amdgcn_mfma_f32_16x16x32_bf16(aD[4 + s], r1[s], acc, 0, 0, 0);
          if (j < 7) {
#pragma unroll
            for (int s = 0; s < 4; ++s) r1[s] = LDW3(j + 1, 4 + s);
          }

          const int nt = w + j * 16;  // h index
          float b3j = sm.b3[nbase + j * 256];
          float p[4];
#pragma unroll
          for (int v = 0; v < 4; ++v) {
            float o = acc[v] + b3j;
            float e2 = __expf(2.0f * o);
            float T = 1.0f - 2.0f / (e2 + 1.0f);
            p[v] = T * dxr[v];
          }
#pragma unroll
          for (int m = 1; m < 16; m <<= 1) {
#pragma unroll
            for (int v = 0; v < 4; ++v) p[v] += __shfl_xor(p[v], m);
          }
          if (row16 == 0) {
#pragma unroll
            for (int v = 0; v < 4; ++v) dest[kg * 4 + v][nt] = p[v];
          }
        }
      }
      __syncthreads();
    }

    // ---- Heun update + store prefetched dx for step k+1
    for (int i = tid; i < G * HH; i += NTHR) {
      int r = i >> 7, c = i & (HH - 1);
      sm.Y[r][c] += 0.5f * dt * (sm.K1[r][c] + sm.F[r][c]);
    }
    if (tid >= 512) {
      int q = tid - 512;
      int which = q >> 8, rr = (q >> 4) & 15, d = q & 15;
      sm.dx[(k + 1) & 1][which][rr][d] = pc2 + 2.0f * ptau * pc1 + 3.0f * ptau * ptau * pc0;
    }
    __syncthreads();
  }

  // ---- classifier + softmax
  if (tid < G * NLBL) {
    int r = tid / NLBL, c = tid % NLBL;
    float s = bl2[c];
    const float* wr = Wl2 + (size_t)c * HH;
#pragma unroll 4
    for (int h = 0; h < HH; ++h) s += sm.Y[r][h] * wr[h];
    sm.logits[tid] = s;
  }
  __syncthreads();
  if (tid < G) {
    float mx = -1e30f;
#pragma unroll
    for (int c = 0; c < NLBL; ++c) mx = fmaxf(mx, sm.logits[tid * NLBL + c]);
    float e[NLBL], sum = 0.f;
#pragma unroll
    for (int c = 0; c < NLBL; ++c) { e[c] = expf(sm.logits[tid * NLBL + c] - mx); sum += e[c]; }
    float inv = 1.0f / sum;
#pragma unroll
    for (int c = 0; c < NLBL; ++c) out[(size_t)(gb + tid) * NLBL + c] = e[c] * inv;
  }
}

extern "C" void kernel_launch(void* const* d_in, const int* in_sizes, int n_in,
                              void* d_out, int out_size, void* d_ws, size_t ws_size,
                              hipStream_t stream) {
  (void)in_sizes; (void)n_in; (void)out_size; (void)ws_size;
  const float* ts = (const float*)d_in[0];
  const float* coeffs = (const float*)d_in[1];
  const float* x0 = (const float*)d_in[2];
  const float* W1 = (const float*)d_in[3];
  const float* b1 = (const float*)d_in[4];
  const float* W2 = (const float*)d_in[5];
  const float* b2 = (const float*)d_in[6];
  const float* W3 = (const float*)d_in[7];
  const float* b3 = (const float*)d_in[8];
  const float* Wl1 = (const float*)d_in[9];
  const float* bl1 = (const float*)d_in[10];
  const float* Wl2 = (const float*)d_in[11];
  const float* bl2 = (const float*)d_in[12];

  unsigned short* w3b = (unsigned short*)d_ws;                 // 524288 bf16
  unsigned short* w2b = w3b + (HH * DD * WD);                  // 65536 bf16
  unsigned short* w1b = w2b + (WD * WD);                       // 32768 bf16

  static_assert(sizeof(SM) <= 160 * 1024, "LDS overflow");
  hipFuncSetAttribute(reinterpret_cast<const void*>(cde_main),
                      hipFuncAttributeMaxDynamicSharedMemorySize, (int)sizeof(SM));

  prep<<<2048, 256, 0, stream>>>(W1, W2, W3, w1b, w2b, w3b);
  cde_main<<<NWG, NTHR, sizeof(SM), stream>>>(ts, coeffs, x0, b1, b2, b3, Wl1, bl1, Wl2, bl2,
                                              w1b, w2b, w3b, (float*)d_out);
}

// Round 4
// 28875.681 us; speedup vs baseline: 1.0585x; 1.0551x over previous
//
#include <hip/hip_runtime.h>

#define BB 512
#define LL 2000
#define DD 16
#define HH 128
#define WD 256
#define NLBL 10
#define NSTEPS 500
#define G 16
#define NWG (BB / G)
#define NTHR 1024

typedef __bf16 bf16x8 __attribute__((ext_vector_type(8)));
typedef float f32x4 __attribute__((ext_vector_type(4)));

__device__ __forceinline__ unsigned short f2bf(float f) {
  unsigned int u = __float_as_uint(f);
  u += 0x7FFFu + ((u >> 16) & 1u);
  return (unsigned short)(u >> 16);
}

// XOR-swizzled element offset into a [rows][256] bf16 LDS tile (16B chunks)
__device__ __forceinline__ int swz(int r, int c) {
  return r * WD + ((((c >> 3) ^ (r & 7)) << 3) | (c & 7));
}

__device__ __forceinline__ bf16x8 ldfrag(const unsigned short* buf, int row, int chunk) {
  return *reinterpret_cast<const bf16x8*>(buf + row * WD + ((chunk ^ (row & 7)) << 3));
}

struct __align__(16) SM {
  float Y[G][HH];
  float K1[G][HH];
  float F[G][HH];
  unsigned short X[G * WD];    // swizzled bf16 activations (input / H2)
  unsigned short Hb[G * WD];   // swizzled bf16 H1
  float dx[2][2][G][DD];       // [step&1][stage][row][d]
  float b1[WD], b2[WD];
  float b3[HH * DD];
  float tsl[LL];
  float tau_tab[2 * NSTEPS];
  unsigned short idx_tab[2 * NSTEPS];
  float logits[G * NLBL];
  unsigned short w1[WD * HH];  // swizzled bf16 W1 (B-fragments), 64KB
};

__global__ void prep(const float* __restrict__ W1, const float* __restrict__ W2,
                     const float* __restrict__ W3,
                     unsigned short* __restrict__ w1b, unsigned short* __restrict__ w2b,
                     unsigned short* __restrict__ w3b) {
  int i = blockIdx.x * blockDim.x + threadIdx.x;
  if (i < HH * DD * WD) w3b[i] = f2bf(W3[i]);
  if (i < WD * WD) w2b[i] = f2bf(W2[i]);
  if (i < WD * HH) w1b[i] = f2bf(W1[i]);
}

__global__ __launch_bounds__(NTHR, 4) void cde_main(
    const float* __restrict__ ts, const float* __restrict__ coeffs,
    const float* __restrict__ x0,
    const float* __restrict__ b1g, const float* __restrict__ b2g, const float* __restrict__ b3g,
    const float* __restrict__ Wl1, const float* __restrict__ bl1,
    const float* __restrict__ Wl2, const float* __restrict__ bl2,
    const unsigned short* __restrict__ w1b, const unsigned short* __restrict__ w2b,
    const unsigned short* __restrict__ w3b,
    float* __restrict__ out) {
  extern __shared__ char smraw[];
  SM& sm = *reinterpret_cast<SM*>(smraw);
  const int tid = threadIdx.x;
  const int gb = blockIdx.x * G;
  const int w = tid >> 6, lane = tid & 63;
  const int row16 = lane & 15, kg = lane >> 4;

  const float ts0 = ts[0];
  const float dt = (ts[LL - 1] - ts0) / (float)NSTEPS;

  // ---- prologue stage 1: LDS fills with no cross-deps
  for (int i = tid; i < LL; i += NTHR) sm.tsl[i] = ts[i];
  for (int i = tid; i < WD; i += NTHR) { sm.b1[i] = b1g[i]; sm.b2[i] = b2g[i]; }
  for (int i = tid; i < HH * DD; i += NTHR) sm.b3[i] = b3g[i];
  // W1 -> LDS, swizzled 16B chunks: row n (256B), chunk kc -> kc^(n&7)
  {
    const uint4* w1p4 = reinterpret_cast<const uint4*>(w1b);
    for (int i = tid; i < WD * HH / 8; i += NTHR) {
      int n = i >> 4, kc = i & 15;
      uint4 v = w1p4[i];
      *reinterpret_cast<uint4*>(&sm.w1[n * HH + (((kc ^ (n & 7)) << 3))]) = v;
    }
  }
  // y0 = x0 @ Wl1^T + bl1
  for (int i = tid; i < G * HH; i += NTHR) {
    int r = i >> 7, h = i & (HH - 1);
    float s = bl1[h];
    const float* xr = x0 + (size_t)(gb + r) * DD;
    const float* wr = Wl1 + (size_t)h * DD;
#pragma unroll
    for (int d = 0; d < DD; ++d) s += xr[d] * wr[d];
    sm.Y[r][h] = s;
  }
  // persistent W2 B-fragments (32 VGPR): wave owns N-tile n = w*16+row16
  bf16x8 w2f[8];
  const uint4* w2p = reinterpret_cast<const uint4*>(w2b);
  const uint4* w3p = reinterpret_cast<const uint4*>(w3b);
  {
    int n = w * 16 + row16;
#pragma unroll
    for (int s = 0; s < 8; ++s) w2f[s] = __builtin_bit_cast(bf16x8, w2p[n * 32 + s * 4 + kg]);
  }
  __syncthreads();

  // ---- prologue stage 2: idx/tau tables (bit-faithful to reference arithmetic)
  for (int e = tid; e < 2 * NSTEPS; e += NTHR) {
    int kk = e >> 1;
    float t = ts0 + (float)kk * dt;
    if (e & 1) t = t + dt;
    int lo = 0, hi = LL;
    while (lo < hi) { int m = (lo + hi) >> 1; if (sm.tsl[m] <= t) lo = m + 1; else hi = m; }
    int idx = lo - 1;
    if (idx < 0) idx = 0;
    if (idx > LL - 2) idx = LL - 2;
    sm.idx_tab[e] = (unsigned short)idx;
    sm.tau_tab[e] = t - sm.tsl[idx];
  }
  __syncthreads();

  // ---- prologue stage 3: dx for step 0 (both stages)
  if (tid >= 512) {
    int q = tid - 512;
    int which = q >> 8, rr = (q >> 4) & 15, d = q & 15;
    int idx = sm.idx_tab[which];
    float tau = sm.tau_tab[which];
    const float* cb = coeffs + ((size_t)(gb + rr) * 4 * (LL - 1) + idx) * DD + d;
    float c0 = cb[0];
    float c1 = cb[(size_t)(LL - 1) * DD];
    float c2 = cb[(size_t)2 * (LL - 1) * DD];
    sm.dx[0][which][rr][d] = c2 + 2.0f * tau * c1 + 3.0f * tau * tau * c0;
  }
  __syncthreads();

  const int nbase = w * 16 + row16;                 // phase-D W3 row base
  const uint4* w3base = w3p + (size_t)nbase * 32 + kg;
#define LDW3(j, f) __builtin_bit_cast(bf16x8, w3base[(size_t)(j) * 8192 + (f) * 4])

  float pc0 = 0.f, pc1 = 0.f, pc2 = 0.f, ptau = 0.f;  // next-step coeff prefetch

  for (int k = 0; k < NSTEPS; ++k) {
    for (int mode = 0; mode < 2; ++mode) {
      float(*dest)[HH] = mode ? sm.F : sm.K1;

      // ---- phase A: stage activations (bf16, swizzled); issue next-step coeff loads
      for (int i = tid; i < G * HH; i += NTHR) {
        int r = i >> 7, c = i & (HH - 1);
        float v = sm.Y[r][c];
        if (mode) v += dt * sm.K1[r][c];
        sm.X[swz(r, c)] = f2bf(v);
      }
      if (mode == 0 && tid >= 512) {
        int q = tid - 512;
        int which = q >> 8, rr = (q >> 4) & 15, d = q & 15;
        int e = 2 * (k + 1) + which;
        if (e > 2 * NSTEPS - 1) e = 2 * NSTEPS - 1;
        int idx = sm.idx_tab[e];
        ptau = sm.tau_tab[e];
        const float* cb = coeffs + ((size_t)(gb + rr) * 4 * (LL - 1) + idx) * DD + d;
        pc0 = cb[0];
        pc1 = cb[(size_t)(LL - 1) * DD];
        pc2 = cb[(size_t)2 * (LL - 1) * DD];
      }
      __syncthreads();

      // ---- phase B: H1 = relu(X @ W1^T + b1)  (W1 frags from LDS)
      {
        const int n = w * 16 + row16;
        f32x4 acc = {0.f, 0.f, 0.f, 0.f};
#pragma unroll
        for (int s = 0; s < 4; ++s) {
          bf16x8 a = ldfrag(sm.X, row16, s * 4 + kg);
          bf16x8 b = *reinterpret_cast<const bf16x8*>(
              &sm.w1[n * HH + ((((s * 4 + kg) ^ (n & 7)) << 3))]);
          acc = __builtin_amdgcn_mfma_f32_16x16x32_bf16(a, b, acc, 0, 0, 0);
        }
#pragma unroll
        for (int v = 0; v < 4; ++v) {
          int r = kg * 4 + v;
          float o = acc[v] + sm.b1[n];
          sm.Hb[swz(r, n)] = f2bf(fmaxf(o, 0.f));
        }
      }
      __syncthreads();

      // ---- phase C: H2 = relu(H1 @ W2^T + b2) -> X
      {
        const int n = w * 16 + row16;
        f32x4 acc = {0.f, 0.f, 0.f, 0.f};
#pragma unroll
        for (int s = 0; s < 8; ++s) {
          bf16x8 a = ldfrag(sm.Hb, row16, s * 4 + kg);
          acc = __builtin_amdgcn_mfma_f32_16x16x32_bf16(a, w2f[s], acc, 0, 0, 0);
        }
#pragma unroll
        for (int v = 0; v < 4; ++v) {
          int r = kg * 4 + v;
          float o = acc[v] + sm.b2[n];
          sm.X[swz(r, n)] = f2bf(fmaxf(o, 0.f));
        }
      }
      __syncthreads();

      // ---- phase D: O = tanh(H2 @ W3^T + b3); F = sum_d O*dX
      // A-fragments read from LDS per use (keeps VGPRs for the W3 ring)
      {
        float dxr[4];
#pragma unroll
        for (int v = 0; v < 4; ++v) dxr[v] = sm.dx[k & 1][mode][kg * 4 + v][row16];

        // 8-deep W3 pipeline: two 4-frag ring buffers, refill right after use
        bf16x8 r0[4], r1[4];
#pragma unroll
        for (int s = 0; s < 4; ++s) r0[s] = LDW3(0, s);
#pragma unroll
        for (int s = 0; s < 4; ++s) r1[s] = LDW3(0, 4 + s);

#pragma unroll
        for (int j = 0; j < 8; ++j) {
          f32x4 acc = {0.f, 0.f, 0.f, 0.f};
#pragma unroll
          for (int s = 0; s < 4; ++s) {
            bf16x8 a = ldfrag(sm.X, row16, s * 4 + kg);
            acc = __builtin_amdgcn_mfma_f32_16x16x32_bf16(a, r0[s], acc, 0, 0, 0);
          }
          if (j < 7) {
#pragma unroll
            for (int s = 0; s < 4; ++s) r0[s] = LDW3(j + 1, s);
          }
#pragma unroll
          for (int s = 0; s < 4; ++s) {
            bf16x8 a = ldfrag(sm.X, row16, (4 + s) * 4 + kg);
            acc = __builtin_amdgcn_mfma_f32_16x16x32_bf16(a, r1[s], acc, 0, 0, 0);
          }
          if (j < 7) {
#pragma unroll
            for (int s = 0; s < 4; ++s) r1[s] = LDW3(j + 1, 4 + s);
          }

          const int nt = w + j * 16;  // h index
          float b3j = sm.b3[nbase + j * 256];
          float p[4];
#pragma unroll
          for (int v = 0; v < 4; ++v) {
            float o = acc[v] + b3j;
            float e2 = __expf(2.0f * o);
            float T = 1.0f - 2.0f / (e2 + 1.0f);
            p[v] = T * dxr[v];
          }
#pragma unroll
          for (int m = 1; m < 16; m <<= 1) {
#pragma unroll
            for (int v = 0; v < 4; ++v) p[v] += __shfl_xor(p[v], m);
          }
          if (row16 == 0) {
#pragma unroll
            for (int v = 0; v < 4; ++v) dest[kg * 4 + v][nt] = p[v];
          }
        }
      }
      __syncthreads();
    }

    // ---- Heun update + store prefetched dx for step k+1
    for (int i = tid; i < G * HH; i += NTHR) {
      int r = i >> 7, c = i & (HH - 1);
      sm.Y[r][c] += 0.5f * dt * (sm.K1[r][c] + sm.F[r][c]);
    }
    if (tid >= 512) {
      int q = tid - 512;
      int which = q >> 8, rr = (q >> 4) & 15, d = q & 15;
      sm.dx[(k + 1) & 1][which][rr][d] = pc2 + 2.0f * ptau * pc1 + 3.0f * ptau * ptau * pc0;
    }
    __syncthreads();
  }

  // ---- classifier + softmax
  if (tid < G * NLBL) {
    int r = tid / NLBL, c = tid % NLBL;
    float s = bl2[c];
    const float* wr = Wl2 + (size_t)c * HH;
#pragma unroll 4
    for (int h = 0; h < HH; ++h) s += sm.Y[r][h] * wr[h];
    sm.logits[tid] = s;
  }
  __syncthreads();
  if (tid < G) {
    float mx = -1e30f;
#pragma unroll
    for (int c = 0; c < NLBL; ++c) mx = fmaxf(mx, sm.logits[tid * NLBL + c]);
    float e[NLBL], sum = 0.f;
#pragma unroll
    for (int c = 0; c < NLBL; ++c) { e[c] = expf(sm.logits[tid * NLBL + c] - mx); sum += e[c]; }
    float inv = 1.0f / sum;
#pragma unroll
    for (int c = 0; c < NLBL; ++c) out[(size_t)(gb + tid) * NLBL + c] = e[c] * inv;
  }
}

extern "C" void kernel_launch(void* const* d_in, const int* in_sizes, int n_in,
                              void* d_out, int out_size, void* d_ws, size_t ws_size,
                              hipStream_t stream) {
  (void)in_sizes; (void)n_in; (void)out_size; (void)ws_size;
  const float* ts = (const float*)d_in[0];
  const float* coeffs = (const float*)d_in[1];
  const float* x0 = (const float*)d_in[2];
  const float* W1 = (const float*)d_in[3];
  const float* b1 = (const float*)d_in[4];
  const float* W2 = (const float*)d_in[5];
  const float* b2 = (const float*)d_in[6];
  const float* W3 = (const float*)d_in[7];
  const float* b3 = (const float*)d_in[8];
  const float* Wl1 = (const float*)d_in[9];
  const float* bl1 = (const float*)d_in[10];
  const float* Wl2 = (const float*)d_in[11];
  const float* bl2 = (const float*)d_in[12];

  unsigned short* w3b = (unsigned short*)d_ws;                 // 524288 bf16
  unsigned short* w2b = w3b + (HH * DD * WD);                  // 65536 bf16
  unsigned short* w1b = w2b + (WD * WD);                       // 32768 bf16

  static_assert(sizeof(SM) <= 160 * 1024, "LDS overflow");
  hipFuncSetAttribute(reinterpret_cast<const void*>(cde_main),
                      hipFuncAttributeMaxDynamicSharedMemorySize, (int)sizeof(SM));

  prep<<<2048, 256, 0, stream>>>(W1, W2, W3, w1b, w2b, w3b);
  cde_main<<<NWG, NTHR, sizeof(SM), stream>>>(ts, coeffs, x0, b1, b2, b3, Wl1, bl1, Wl2, bl2,
                                              w1b, w2b, w3b, (float*)d_out);
}

// Round 6
// 21694.321 us; speedup vs baseline: 1.4089x; 1.3310x over previous
//
#include <hip/hip_runtime.h>

#define BB 512
#define LL 2000
#define DD 16
#define HH 128
#define WD 256
#define NLBL 10
#define NSTEPS 500
#define G 16
#define NWG (BB / G)
#define NTHR 512

typedef __bf16 bf16x8 __attribute__((ext_vector_type(8)));
typedef float f32x4 __attribute__((ext_vector_type(4)));

__device__ __forceinline__ unsigned short f2bf(float f) {
  unsigned int u = __float_as_uint(f);
  u += 0x7FFFu + ((u >> 16) & 1u);
  return (unsigned short)(u >> 16);
}

// XOR-swizzled element offset into a [rows][256] bf16 LDS tile (16B chunks)
__device__ __forceinline__ int swz(int r, int c) {
  return r * WD + ((((c >> 3) ^ (r & 7)) << 3) | (c & 7));
}

__device__ __forceinline__ bf16x8 ldfrag(const unsigned short* buf, int row, int chunk) {
  return *reinterpret_cast<const bf16x8*>(buf + row * WD + ((chunk ^ (row & 7)) << 3));
}

// OCP e4m3fn encode, RNE (runs in prep only)
__device__ unsigned char enc_e4m3(float x) {
  float ax = fabsf(x);
  unsigned char sg = (unsigned char)((__float_as_uint(x) >> 24) & 0x80u);
  if (ax > 448.f) ax = 448.f;
  if (ax < 0.001953125f) {  // below min subnormal step 2^-9
    int m = (int)rintf(ax * 512.f);  // 0 or 1
    return sg | (unsigned char)m;
  }
  unsigned int u = __float_as_uint(ax);
  unsigned int r = u + 0x7FFFFu + ((u >> 20) & 1u);  // RNE to 3-bit mantissa
  r &= 0xFFF00000u;
  int e = (int)(r >> 23) - 127;
  if (e < -6) {  // subnormal
    int m = (int)rintf(ax * 512.f);
    if (m >= 8) return sg | 0x08;
    return sg | (unsigned char)m;
  }
  if (e > 8) return sg | 0x7E;  // 448
  unsigned int m = (r >> 20) & 7u;
  return sg | (unsigned char)(((e + 7) << 3) | m);
}

// decode 8 fp8 bytes -> bf16x8, scaled by s4
__device__ __forceinline__ bf16x8 dec8(uint2 u, float s4) {
#if __has_builtin(__builtin_amdgcn_cvt_pk_f32_fp8)
  auto f0 = __builtin_amdgcn_cvt_pk_f32_fp8((int)u.x, false);
  auto f1 = __builtin_amdgcn_cvt_pk_f32_fp8((int)u.x, true);
  auto f2 = __builtin_amdgcn_cvt_pk_f32_fp8((int)u.y, false);
  auto f3 = __builtin_amdgcn_cvt_pk_f32_fp8((int)u.y, true);
  bf16x8 r = {(__bf16)(f0[0] * s4), (__bf16)(f0[1] * s4), (__bf16)(f1[0] * s4), (__bf16)(f1[1] * s4),
              (__bf16)(f2[0] * s4), (__bf16)(f2[1] * s4), (__bf16)(f3[0] * s4), (__bf16)(f3[1] * s4)};
  return r;
#else
  float rr[8];
#pragma unroll
  for (int i = 0; i < 8; ++i) {
    unsigned int byte = ((i < 4 ? u.x >> (8 * i) : u.y >> (8 * (i - 4)))) & 0xFFu;
    unsigned int e = (byte >> 3) & 15u, m = byte & 7u;
    float v = e ? __uint_as_float(((e + 120u) << 23) | (m << 20)) : (float)m * 0.001953125f;
    rr[i] = (byte & 0x80u) ? -v : v;
  }
  bf16x8 r = {(__bf16)(rr[0] * s4), (__bf16)(rr[1] * s4), (__bf16)(rr[2] * s4), (__bf16)(rr[3] * s4),
              (__bf16)(rr[4] * s4), (__bf16)(rr[5] * s4), (__bf16)(rr[6] * s4), (__bf16)(rr[7] * s4)};
  return r;
#endif
}

struct __align__(16) SM {
  float Y[G][HH];
  float K1[G][HH];
  float F[G][HH];
  unsigned short X[G * WD];    // swizzled bf16 activations (input / H2)
  unsigned short Hb[G * WD];   // swizzled bf16 H1
  float dx[2][2][G][DD];       // [step&1][stage][row][d]
  float b1[WD], b2[WD];
  float2 sb3[HH * DD];         // {w3 row scale, b3}
  float tsl[LL];
  float tau_tab[2 * NSTEPS];
  unsigned short idx_tab[2 * NSTEPS];
  float logits[G * NLBL];
};

// per-row absmax -> scale = max/240
__global__ void prep_scale(const float* __restrict__ W3, float* __restrict__ w3s) {
  int row = blockIdx.x * 4 + (threadIdx.x >> 6);
  int lane = threadIdx.x & 63;
  const float* wr = W3 + (size_t)row * WD;
  float m = 0.f;
#pragma unroll
  for (int i = 0; i < 4; ++i) m = fmaxf(m, fabsf(wr[lane + 64 * i]));
#pragma unroll
  for (int off = 32; off >= 1; off >>= 1) m = fmaxf(m, __shfl_xor(m, off));
  if (lane == 0) w3s[row] = fmaxf(m, 1e-30f) * (1.0f / 240.0f);
}

// pack W3 into frag-major fp8: out uint2 index o = nt*512 + s*64 + lane
// holds bytes k = s*32 + (lane>>4)*8 + j of row nt*16 + (lane&15)
__global__ void prep_pack(const float* __restrict__ W3, const float* __restrict__ w3s,
                          uint2* __restrict__ q8) {
  int o = blockIdx.x * blockDim.x + threadIdx.x;  // 65536
  int lane = o & 63, s = (o >> 6) & 7, nt = o >> 9;
  int row = nt * 16 + (lane & 15);
  int k0 = s * 32 + ((lane >> 4) << 3);
  float inv = 1.0f / w3s[row];
  const float* src = W3 + (size_t)row * WD + k0;
  unsigned int lo = 0, hi = 0;
#pragma unroll
  for (int j = 0; j < 4; ++j) lo |= (unsigned int)enc_e4m3(src[j] * inv) << (8 * j);
#pragma unroll
  for (int j = 0; j < 4; ++j) hi |= (unsigned int)enc_e4m3(src[4 + j] * inv) << (8 * j);
  q8[o] = make_uint2(lo, hi);
}

__global__ void prep_w12(const float* __restrict__ W1, const float* __restrict__ W2,
                         unsigned short* __restrict__ w1b, unsigned short* __restrict__ w2b) {
  int i = blockIdx.x * blockDim.x + threadIdx.x;
  if (i < WD * WD) w2b[i] = f2bf(W2[i]);
  if (i < WD * HH) w1b[i] = f2bf(W1[i]);
}

// ---- phase D macros: static ring-slot indices (rule: no runtime-indexed reg arrays)
#define PD_ISSUE(RB, J)                                                      \
  if ((J) < 16) {                                                            \
    const uint2* src_ = q8v + (((size_t)(w + (J) * 8)) << 9) + lane;         \
    RB[0] = src_[0];   RB[1] = src_[64];  RB[2] = src_[128]; RB[3] = src_[192]; \
    RB[4] = src_[256]; RB[5] = src_[320]; RB[6] = src_[384]; RB[7] = src_[448]; \
  }

#define PD_PROC(RB, J)                                                       \
  {                                                                          \
    const int nt_ = w + (J) * 8;                                             \
    const float2 sb_ = sm.sb3[nt_ * 16 + row16];                             \
    f32x4 acc = {0.f, 0.f, 0.f, 0.f};                                        \
    _Pragma("unroll") for (int s_ = 0; s_ < 8; ++s_) {                       \
      acc = __builtin_amdgcn_mfma_f32_16x16x32_bf16(aD[s_], dec8(RB[s_], sb_.x), acc, 0, 0, 0); \
    }                                                                        \
    float p_[4];                                                             \
    _Pragma("unroll") for (int v_ = 0; v_ < 4; ++v_) {                       \
      float o_ = acc[v_] + sb_.y;                                            \
      float e2_ = __expf(2.0f * o_);                                         \
      float T_ = 1.0f - 2.0f / (e2_ + 1.0f);                                 \
      p_[v_] = T_ * dxr[v_];                                                 \
    }                                                                        \
    _Pragma("unroll") for (int m_ = 1; m_ < 16; m_ <<= 1) {                  \
      _Pragma("unroll") for (int v_ = 0; v_ < 4; ++v_) p_[v_] += __shfl_xor(p_[v_], m_); \
    }                                                                        \
    if (row16 == 0) {                                                        \
      _Pragma("unroll") for (int v_ = 0; v_ < 4; ++v_) dest[kg * 4 + v_][nt_] = p_[v_]; \
    }                                                                        \
  }

__global__ __launch_bounds__(NTHR, 2) void cde_main(
    const float* __restrict__ ts, const float* __restrict__ coeffs,
    const float* __restrict__ x0,
    const float* __restrict__ b1g, const float* __restrict__ b2g, const float* __restrict__ b3g,
    const float* __restrict__ Wl1, const float* __restrict__ bl1,
    const float* __restrict__ Wl2, const float* __restrict__ bl2,
    const unsigned short* __restrict__ w1b, const unsigned short* __restrict__ w2b,
    const uint2* __restrict__ q8v, const float* __restrict__ w3s,
    float* __restrict__ out) {
  extern __shared__ char smraw[];
  SM& sm = *reinterpret_cast<SM*>(smraw);
  const int tid = threadIdx.x;
  const int gb = blockIdx.x * G;
  const int w = tid >> 6, lane = tid & 63;
  const int row16 = lane & 15, kg = lane >> 4;

  const float ts0 = ts[0];
  const float dt = (ts[LL - 1] - ts0) / (float)NSTEPS;

  // ---- prologue: LDS fills
  for (int i = tid; i < LL; i += NTHR) sm.tsl[i] = ts[i];
  for (int i = tid; i < WD; i += NTHR) { sm.b1[i] = b1g[i]; sm.b2[i] = b2g[i]; }
  for (int i = tid; i < HH * DD; i += NTHR) sm.sb3[i] = make_float2(w3s[i], b3g[i]);

  // y0 = x0 @ Wl1^T + bl1
  for (int i = tid; i < G * HH; i += NTHR) {
    int r = i >> 7, h = i & (HH - 1);
    float s = bl1[h];
    const float* xr = x0 + (size_t)(gb + r) * DD;
    const float* wr = Wl1 + (size_t)h * DD;
#pragma unroll
    for (int d = 0; d < DD; ++d) s += xr[d] * wr[d];
    sm.Y[r][h] = s;
  }

  // persistent W1/W2 B-fragments: wave owns two N-tiles n = (w+tt*8)*16+row16
  bf16x8 w1f[2][4], w2f[2][8];
  const uint4* w1p = reinterpret_cast<const uint4*>(w1b);
  const uint4* w2p = reinterpret_cast<const uint4*>(w2b);
#pragma unroll
  for (int tt = 0; tt < 2; ++tt) {
    int n = (w + tt * 8) * 16 + row16;
#pragma unroll
    for (int s = 0; s < 4; ++s) w1f[tt][s] = __builtin_bit_cast(bf16x8, w1p[n * 16 + s * 4 + kg]);
#pragma unroll
    for (int s = 0; s < 8; ++s) w2f[tt][s] = __builtin_bit_cast(bf16x8, w2p[n * 32 + s * 4 + kg]);
  }
  __syncthreads();

  // idx/tau tables, bit-faithful to reference time arithmetic
  for (int e = tid; e < 2 * NSTEPS; e += NTHR) {
    int kk = e >> 1;
    float t = ts0 + (float)kk * dt;
    if (e & 1) t = t + dt;
    int lo = 0, hi = LL;
    while (lo < hi) { int m = (lo + hi) >> 1; if (sm.tsl[m] <= t) lo = m + 1; else hi = m; }
    int idx = lo - 1;
    if (idx < 0) idx = 0;
    if (idx > LL - 2) idx = LL - 2;
    sm.idx_tab[e] = (unsigned short)idx;
    sm.tau_tab[e] = t - sm.tsl[idx];
  }
  __syncthreads();

  // dx for step 0 (both stages): 512 threads cover 2*16*16
  {
    int which = tid >> 8, rr = (tid >> 4) & 15, d = tid & 15;
    int idx = sm.idx_tab[which];
    float tau = sm.tau_tab[which];
    const float* cb = coeffs + ((size_t)(gb + rr) * 4 * (LL - 1) + idx) * DD + d;
    float c0 = cb[0];
    float c1 = cb[(size_t)(LL - 1) * DD];
    float c2 = cb[(size_t)2 * (LL - 1) * DD];
    sm.dx[0][which][rr][d] = c2 + 2.0f * tau * c1 + 3.0f * tau * tau * c0;
  }
  __syncthreads();

  float pc0 = 0.f, pc1 = 0.f, pc2 = 0.f, ptau = 0.f;  // next-step coeff prefetch

  for (int k = 0; k < NSTEPS; ++k) {
    for (int mode = 0; mode < 2; ++mode) {
      float(*dest)[HH] = mode ? sm.F : sm.K1;

      // ---- issue first two W3 fp8 tiles (no deps on LDS phases)
      uint2 rb0[8], rb1[8], rb2[8], rb3[8];
      PD_ISSUE(rb0, 0)
      PD_ISSUE(rb1, 1)

      // ---- phase A: stage activations (bf16, swizzled); next-step coeff prefetch
      for (int i = tid; i < G * HH; i += NTHR) {
        int r = i >> 7, c = i & (HH - 1);
        float v = sm.Y[r][c];
        if (mode) v += dt * sm.K1[r][c];
        sm.X[swz(r, c)] = f2bf(v);
      }
      if (mode == 0) {
        int which = tid >> 8, rr = (tid >> 4) & 15, d = tid & 15;
        int e = 2 * (k + 1) + which;
        if (e > 2 * NSTEPS - 1) e = 2 * NSTEPS - 1;
        int idx = sm.idx_tab[e];
        ptau = sm.tau_tab[e];
        const float* cb = coeffs + ((size_t)(gb + rr) * 4 * (LL - 1) + idx) * DD + d;
        pc0 = cb[0];
        pc1 = cb[(size_t)(LL - 1) * DD];
        pc2 = cb[(size_t)2 * (LL - 1) * DD];
      }
      __syncthreads();

      // ---- phase B: H1 = relu(X @ W1^T + b1)
#pragma unroll
      for (int tt = 0; tt < 2; ++tt) {
        const int n = (w + tt * 8) * 16 + row16;
        f32x4 acc = {0.f, 0.f, 0.f, 0.f};
#pragma unroll
        for (int s = 0; s < 4; ++s) {
          bf16x8 a = ldfrag(sm.X, row16, s * 4 + kg);
          acc = __builtin_amdgcn_mfma_f32_16x16x32_bf16(a, w1f[tt][s], acc, 0, 0, 0);
        }
#pragma unroll
        for (int v = 0; v < 4; ++v) {
          int r = kg * 4 + v;
          float o = acc[v] + sm.b1[n];
          sm.Hb[swz(r, n)] = f2bf(fmaxf(o, 0.f));
        }
      }
      __syncthreads();

      // ---- phase C: H2 = relu(H1 @ W2^T + b2) -> X
#pragma unroll
      for (int tt = 0; tt < 2; ++tt) {
        const int n = (w + tt * 8) * 16 + row16;
        f32x4 acc = {0.f, 0.f, 0.f, 0.f};
#pragma unroll
        for (int s = 0; s < 8; ++s) {
          bf16x8 a = ldfrag(sm.Hb, row16, s * 4 + kg);
          acc = __builtin_amdgcn_mfma_f32_16x16x32_bf16(a, w2f[tt][s], acc, 0, 0, 0);
        }
#pragma unroll
        for (int v = 0; v < 4; ++v) {
          int r = kg * 4 + v;
          float o = acc[v] + sm.b2[n];
          sm.X[swz(r, n)] = f2bf(fmaxf(o, 0.f));
        }
      }
      __syncthreads();

      // ---- phase D: O = tanh(H2 @ W3^T + b3); F = sum_d O*dX
      {
        bf16x8 aD[8];
#pragma unroll
        for (int s = 0; s < 8; ++s) aD[s] = ldfrag(sm.X, row16, s * 4 + kg);
        float dxr[4];
#pragma unroll
        for (int v = 0; v < 4; ++v) dxr[v] = sm.dx[k & 1][mode][kg * 4 + v][row16];

        for (int jj = 0; jj < 16; jj += 4) {
          PD_ISSUE(rb2, jj + 2)
          PD_PROC(rb0, jj + 0)
          PD_ISSUE(rb3, jj + 3)
          PD_PROC(rb1, jj + 1)
          PD_ISSUE(rb0, jj + 4)
          PD_PROC(rb2, jj + 2)
          PD_ISSUE(rb1, jj + 5)
          PD_PROC(rb3, jj + 3)
        }
      }
      __syncthreads();
    }

    // ---- Heun update + commit prefetched dx for step k+1
    for (int i = tid; i < G * HH; i += NTHR) {
      int r = i >> 7, c = i & (HH - 1);
      sm.Y[r][c] += 0.5f * dt * (sm.K1[r][c] + sm.F[r][c]);
    }
    {
      int which = tid >> 8, rr = (tid >> 4) & 15, d = tid & 15;
      sm.dx[(k + 1) & 1][which][rr][d] = pc2 + 2.0f * ptau * pc1 + 3.0f * ptau * ptau * pc0;
    }
    __syncthreads();
  }

  // ---- classifier + softmax
  if (tid < G * NLBL) {
    int r = tid / NLBL, c = tid % NLBL;
    float s = bl2[c];
    const float* wr = Wl2 + (size_t)c * HH;
#pragma unroll 4
    for (int h = 0; h < HH; ++h) s += sm.Y[r][h] * wr[h];
    sm.logits[tid] = s;
  }
  __syncthreads();
  if (tid < G) {
    float mx = -1e30f;
#pragma unroll
    for (int c = 0; c < NLBL; ++c) mx = fmaxf(mx, sm.logits[tid * NLBL + c]);
    float e[NLBL], sum = 0.f;
#pragma unroll
    for (int c = 0; c < NLBL; ++c) { e[c] = expf(sm.logits[tid * NLBL + c] - mx); sum += e[c]; }
    float inv = 1.0f / sum;
#pragma unroll
    for (int c = 0; c < NLBL; ++c) out[(size_t)(gb + tid) * NLBL + c] = e[c] * inv;
  }
}

extern "C" void kernel_launch(void* const* d_in, const int* in_sizes, int n_in,
                              void* d_out, int out_size, void* d_ws, size_t ws_size,
                              hipStream_t stream) {
  (void)in_sizes; (void)n_in; (void)out_size; (void)ws_size;
  const float* ts = (const float*)d_in[0];
  const float* coeffs = (const float*)d_in[1];
  const float* x0 = (const float*)d_in[2];
  const float* W1 = (const float*)d_in[3];
  const float* b1 = (const float*)d_in[4];
  const float* W2 = (const float*)d_in[5];
  const float* b2 = (const float*)d_in[6];
  const float* W3 = (const float*)d_in[7];
  const float* b3 = (const float*)d_in[8];
  const float* Wl1 = (const float*)d_in[9];
  const float* bl1 = (const float*)d_in[10];
  const float* Wl2 = (const float*)d_in[11];
  const float* bl2 = (const float*)d_in[12];

  char* ws = (char*)d_ws;
  uint2* q8 = (uint2*)ws;                                   // 512 KB fp8 W3 (frag-major)
  float* w3s = (float*)(ws + 524288);                       // 8 KB row scales
  unsigned short* w2b = (unsigned short*)(ws + 532480);     // 128 KB
  unsigned short* w1b = (unsigned short*)(ws + 663552);     // 64 KB

  static_assert(sizeof(SM) <= 160 * 1024, "LDS overflow");
  hipFuncSetAttribute(reinterpret_cast<const void*>(cde_main),
                      hipFuncAttributeMaxDynamicSharedMemorySize, (int)sizeof(SM));

  prep_scale<<<512, 256, 0, stream>>>(W3, w3s);
  prep_pack<<<256, 256, 0, stream>>>(W3, w3s, q8);
  prep_w12<<<256, 256, 0, stream>>>(W1, W2, w1b, w2b);
  cde_main<<<NWG, NTHR, sizeof(SM), stream>>>(ts, coeffs, x0, b1, b2, b3, Wl1, bl1, Wl2, bl2,
                                              w1b, w2b, q8, w3s, (float*)d_out);
}

// Round 7
// 12388.281 us; speedup vs baseline: 2.4672x; 1.7512x over previous
//
#include <hip/hip_runtime.h>

#define BB 512
#define LL 2000
#define DD 16
#define HH 128
#define WD 256
#define NLBL 10
#define NSTEPS 500
#define G 16
#define NWG (BB / G)
#define NTHR 512

typedef __bf16 bf16x8 __attribute__((ext_vector_type(8)));
typedef float f32x4 __attribute__((ext_vector_type(4)));

__device__ __forceinline__ unsigned short f2bf(float f) {
  unsigned int u = __float_as_uint(f);
  u += 0x7FFFu + ((u >> 16) & 1u);
  return (unsigned short)(u >> 16);
}

// XOR-swizzled element offset into a [rows][256] bf16 LDS tile (16B chunks)
__device__ __forceinline__ int swz(int r, int c) {
  return r * WD + ((((c >> 3) ^ (r & 7)) << 3) | (c & 7));
}

__device__ __forceinline__ bf16x8 ldfrag(const unsigned short* buf, int row, int chunk) {
  return *reinterpret_cast<const bf16x8*>(buf + row * WD + ((chunk ^ (row & 7)) << 3));
}

// OCP e4m3fn encode, RNE (runs in prep only)
__device__ unsigned char enc_e4m3(float x) {
  float ax = fabsf(x);
  unsigned char sg = (unsigned char)((__float_as_uint(x) >> 24) & 0x80u);
  if (ax > 448.f) ax = 448.f;
  if (ax < 0.001953125f) {  // below min subnormal step 2^-9
    int m = (int)rintf(ax * 512.f);  // 0 or 1
    return sg | (unsigned char)m;
  }
  unsigned int u = __float_as_uint(ax);
  unsigned int r = u + 0x7FFFFu + ((u >> 20) & 1u);  // RNE to 3-bit mantissa
  r &= 0xFFF00000u;
  int e = (int)(r >> 23) - 127;
  if (e < -6) {  // subnormal
    int m = (int)rintf(ax * 512.f);
    if (m >= 8) return sg | 0x08;
    return sg | (unsigned char)m;
  }
  if (e > 8) return sg | 0x7E;  // 448
  unsigned int m = (r >> 20) & 7u;
  return sg | (unsigned char)(((e + 7) << 3) | m);
}

// pack 8 bf16 -> 8 fp8 e4m3 bytes (as 64-bit MFMA operand)
__device__ __forceinline__ long pk_fp8(bf16x8 a) {
#if __has_builtin(__builtin_amdgcn_cvt_pk_fp8_f32)
  int w0 = __builtin_amdgcn_cvt_pk_fp8_f32((float)a[0], (float)a[1], 0, false);
  w0 = __builtin_amdgcn_cvt_pk_fp8_f32((float)a[2], (float)a[3], w0, true);
  int w1 = __builtin_amdgcn_cvt_pk_fp8_f32((float)a[4], (float)a[5], 0, false);
  w1 = __builtin_amdgcn_cvt_pk_fp8_f32((float)a[6], (float)a[7], w1, true);
  uint2 u = make_uint2((unsigned int)w0, (unsigned int)w1);
  return __builtin_bit_cast(long, u);
#else
  unsigned int lo = 0, hi = 0;
#pragma unroll
  for (int j = 0; j < 4; ++j) lo |= (unsigned int)enc_e4m3((float)a[j]) << (8 * j);
#pragma unroll
  for (int j = 0; j < 4; ++j) hi |= (unsigned int)enc_e4m3((float)a[4 + j]) << (8 * j);
  uint2 u = make_uint2(lo, hi);
  return __builtin_bit_cast(long, u);
#endif
}

struct __align__(16) SM {
  float Y[G][HH];
  float K1[G][HH];
  float F[G][HH];
  unsigned short X[G * WD];    // swizzled bf16 activations (input / H2)
  unsigned short Hb[G * WD];   // swizzled bf16 H1
  float dx[2][2][G][DD];       // [step&1][stage][row][d]
  float b1[WD], b2[WD];
  float2 sb3[HH * DD];         // {w3 row scale, b3}
  float tsl[LL];
  float tau_tab[2 * NSTEPS];
  unsigned short idx_tab[2 * NSTEPS];
  float logits[G * NLBL];
};

// per-row absmax -> scale = max/240
__global__ void prep_scale(const float* __restrict__ W3, float* __restrict__ w3s) {
  int row = blockIdx.x * 4 + (threadIdx.x >> 6);
  int lane = threadIdx.x & 63;
  const float* wr = W3 + (size_t)row * WD;
  float m = 0.f;
#pragma unroll
  for (int i = 0; i < 4; ++i) m = fmaxf(m, fabsf(wr[lane + 64 * i]));
#pragma unroll
  for (int off = 32; off >= 1; off >>= 1) m = fmaxf(m, __shfl_xor(m, off));
  if (lane == 0) w3s[row] = fmaxf(m, 1e-30f) * (1.0f / 240.0f);
}

// pack W3 into frag-major fp8: out uint2 index o = nt*512 + s*64 + lane
// holds bytes k = s*32 + (lane>>4)*8 + j of row nt*16 + (lane&15)
__global__ void prep_pack(const float* __restrict__ W3, const float* __restrict__ w3s,
                          uint2* __restrict__ q8) {
  int o = blockIdx.x * blockDim.x + threadIdx.x;  // 65536
  int lane = o & 63, s = (o >> 6) & 7, nt = o >> 9;
  int row = nt * 16 + (lane & 15);
  int k0 = s * 32 + ((lane >> 4) << 3);
  float inv = 1.0f / w3s[row];
  const float* src = W3 + (size_t)row * WD + k0;
  unsigned int lo = 0, hi = 0;
#pragma unroll
  for (int j = 0; j < 4; ++j) lo |= (unsigned int)enc_e4m3(src[j] * inv) << (8 * j);
#pragma unroll
  for (int j = 0; j < 4; ++j) hi |= (unsigned int)enc_e4m3(src[4 + j] * inv) << (8 * j);
  q8[o] = make_uint2(lo, hi);
}

__global__ void prep_w12(const float* __restrict__ W1, const float* __restrict__ W2,
                         unsigned short* __restrict__ w1b, unsigned short* __restrict__ w2b) {
  int i = blockIdx.x * blockDim.x + threadIdx.x;
  if (i < WD * WD) w2b[i] = f2bf(W2[i]);
  if (i < WD * HH) w1b[i] = f2bf(W1[i]);
}

// ---- phase D macros: static ring-slot indices (rule: no runtime-indexed reg arrays)
#define PD_ISSUE(RB, J)                                                      \
  if ((J) < 16) {                                                            \
    const uint2* src_ = q8v + (((size_t)(w + (J) * 8)) << 9) + lane;         \
    RB[0] = src_[0];   RB[1] = src_[64];  RB[2] = src_[128]; RB[3] = src_[192]; \
    RB[4] = src_[256]; RB[5] = src_[320]; RB[6] = src_[384]; RB[7] = src_[448]; \
  }

#define PD_PROC(RB, J)                                                       \
  {                                                                          \
    const int nt_ = w + (J) * 8;                                             \
    const float2 sb_ = sm.sb3[nt_ * 16 + row16];                             \
    f32x4 acc = {0.f, 0.f, 0.f, 0.f};                                        \
    _Pragma("unroll") for (int s_ = 0; s_ < 8; ++s_) {                       \
      acc = __builtin_amdgcn_mfma_f32_16x16x32_fp8_fp8(                      \
          a8[s_], __builtin_bit_cast(long, RB[s_]), acc, 0, 0, 0);           \
    }                                                                        \
    float p_[4];                                                             \
    _Pragma("unroll") for (int v_ = 0; v_ < 4; ++v_) {                       \
      float o_ = acc[v_] * sb_.x + sb_.y;                                    \
      float e2_ = __expf(2.0f * o_);                                         \
      float T_ = 1.0f - 2.0f / (e2_ + 1.0f);                                 \
      p_[v_] = T_ * dxr[v_];                                                 \
    }                                                                        \
    _Pragma("unroll") for (int m_ = 1; m_ < 16; m_ <<= 1) {                  \
      _Pragma("unroll") for (int v_ = 0; v_ < 4; ++v_) p_[v_] += __shfl_xor(p_[v_], m_); \
    }                                                                        \
    if (row16 == 0) {                                                        \
      _Pragma("unroll") for (int v_ = 0; v_ < 4; ++v_) dest[kg * 4 + v_][nt_] = p_[v_]; \
    }                                                                        \
  }

__global__ __launch_bounds__(NTHR, 2) void cde_main(
    const float* __restrict__ ts, const float* __restrict__ coeffs,
    const float* __restrict__ x0,
    const float* __restrict__ b1g, const float* __restrict__ b2g, const float* __restrict__ b3g,
    const float* __restrict__ Wl1, const float* __restrict__ bl1,
    const float* __restrict__ Wl2, const float* __restrict__ bl2,
    const unsigned short* __restrict__ w1b, const unsigned short* __restrict__ w2b,
    const uint2* __restrict__ q8v, const float* __restrict__ w3s,
    float* __restrict__ out) {
  extern __shared__ char smraw[];
  SM& sm = *reinterpret_cast<SM*>(smraw);
  const int tid = threadIdx.x;
  const int gb = blockIdx.x * G;
  const int w = tid >> 6, lane = tid & 63;
  const int row16 = lane & 15, kg = lane >> 4;

  const float ts0 = ts[0];
  const float dt = (ts[LL - 1] - ts0) / (float)NSTEPS;

  // ---- prologue: LDS fills
  for (int i = tid; i < LL; i += NTHR) sm.tsl[i] = ts[i];
  for (int i = tid; i < WD; i += NTHR) { sm.b1[i] = b1g[i]; sm.b2[i] = b2g[i]; }
  for (int i = tid; i < HH * DD; i += NTHR) sm.sb3[i] = make_float2(w3s[i], b3g[i]);

  // y0 = x0 @ Wl1^T + bl1
  for (int i = tid; i < G * HH; i += NTHR) {
    int r = i >> 7, h = i & (HH - 1);
    float s = bl1[h];
    const float* xr = x0 + (size_t)(gb + r) * DD;
    const float* wr = Wl1 + (size_t)h * DD;
#pragma unroll
    for (int d = 0; d < DD; ++d) s += xr[d] * wr[d];
    sm.Y[r][h] = s;
  }

  // persistent W1/W2 B-fragments: wave owns two N-tiles n = (w+tt*8)*16+row16
  bf16x8 w1f[2][4], w2f[2][8];
  const uint4* w1p = reinterpret_cast<const uint4*>(w1b);
  const uint4* w2p = reinterpret_cast<const uint4*>(w2b);
#pragma unroll
  for (int tt = 0; tt < 2; ++tt) {
    int n = (w + tt * 8) * 16 + row16;
#pragma unroll
    for (int s = 0; s < 4; ++s) w1f[tt][s] = __builtin_bit_cast(bf16x8, w1p[n * 16 + s * 4 + kg]);
#pragma unroll
    for (int s = 0; s < 8; ++s) w2f[tt][s] = __builtin_bit_cast(bf16x8, w2p[n * 32 + s * 4 + kg]);
  }
  __syncthreads();

  // idx/tau tables, bit-faithful to reference time arithmetic
  for (int e = tid; e < 2 * NSTEPS; e += NTHR) {
    int kk = e >> 1;
    float t = ts0 + (float)kk * dt;
    if (e & 1) t = t + dt;
    int lo = 0, hi = LL;
    while (lo < hi) { int m = (lo + hi) >> 1; if (sm.tsl[m] <= t) lo = m + 1; else hi = m; }
    int idx = lo - 1;
    if (idx < 0) idx = 0;
    if (idx > LL - 2) idx = LL - 2;
    sm.idx_tab[e] = (unsigned short)idx;
    sm.tau_tab[e] = t - sm.tsl[idx];
  }
  __syncthreads();

  // dx for step 0 (both stages): 512 threads cover 2*16*16
  {
    int which = tid >> 8, rr = (tid >> 4) & 15, d = tid & 15;
    int idx = sm.idx_tab[which];
    float tau = sm.tau_tab[which];
    const float* cb = coeffs + ((size_t)(gb + rr) * 4 * (LL - 1) + idx) * DD + d;
    float c0 = cb[0];
    float c1 = cb[(size_t)(LL - 1) * DD];
    float c2 = cb[(size_t)2 * (LL - 1) * DD];
    sm.dx[0][which][rr][d] = c2 + 2.0f * tau * c1 + 3.0f * tau * tau * c0;
  }
  __syncthreads();

  float pc0 = 0.f, pc1 = 0.f, pc2 = 0.f, ptau = 0.f;  // next-step coeff prefetch

  for (int k = 0; k < NSTEPS; ++k) {
    for (int mode = 0; mode < 2; ++mode) {
      float(*dest)[HH] = mode ? sm.F : sm.K1;

      // ---- issue first two W3 fp8 tiles (no deps on LDS phases)
      uint2 rb0[8], rb1[8], rb2[8], rb3[8];
      PD_ISSUE(rb0, 0)
      PD_ISSUE(rb1, 1)

      // ---- phase A: stage activations (bf16, swizzled); next-step coeff prefetch
      for (int i = tid; i < G * HH; i += NTHR) {
        int r = i >> 7, c = i & (HH - 1);
        float v = sm.Y[r][c];
        if (mode) v += dt * sm.K1[r][c];
        sm.X[swz(r, c)] = f2bf(v);
      }
      if (mode == 0) {
        int which = tid >> 8, rr = (tid >> 4) & 15, d = tid & 15;
        int e = 2 * (k + 1) + which;
        if (e > 2 * NSTEPS - 1) e = 2 * NSTEPS - 1;
        int idx = sm.idx_tab[e];
        ptau = sm.tau_tab[e];
        const float* cb = coeffs + ((size_t)(gb + rr) * 4 * (LL - 1) + idx) * DD + d;
        pc0 = cb[0];
        pc1 = cb[(size_t)(LL - 1) * DD];
        pc2 = cb[(size_t)2 * (LL - 1) * DD];
      }
      __syncthreads();

      // ---- phase B: H1 = relu(X @ W1^T + b1)
#pragma unroll
      for (int tt = 0; tt < 2; ++tt) {
        const int n = (w + tt * 8) * 16 + row16;
        f32x4 acc = {0.f, 0.f, 0.f, 0.f};
#pragma unroll
        for (int s = 0; s < 4; ++s) {
          bf16x8 a = ldfrag(sm.X, row16, s * 4 + kg);
          acc = __builtin_amdgcn_mfma_f32_16x16x32_bf16(a, w1f[tt][s], acc, 0, 0, 0);
        }
#pragma unroll
        for (int v = 0; v < 4; ++v) {
          int r = kg * 4 + v;
          float o = acc[v] + sm.b1[n];
          sm.Hb[swz(r, n)] = f2bf(fmaxf(o, 0.f));
        }
      }
      __syncthreads();

      // ---- phase C: H2 = relu(H1 @ W2^T + b2) -> X
#pragma unroll
      for (int tt = 0; tt < 2; ++tt) {
        const int n = (w + tt * 8) * 16 + row16;
        f32x4 acc = {0.f, 0.f, 0.f, 0.f};
#pragma unroll
        for (int s = 0; s < 8; ++s) {
          bf16x8 a = ldfrag(sm.Hb, row16, s * 4 + kg);
          acc = __builtin_amdgcn_mfma_f32_16x16x32_bf16(a, w2f[tt][s], acc, 0, 0, 0);
        }
#pragma unroll
        for (int v = 0; v < 4; ++v) {
          int r = kg * 4 + v;
          float o = acc[v] + sm.b2[n];
          sm.X[swz(r, n)] = f2bf(fmaxf(o, 0.f));
        }
      }
      __syncthreads();

      // ---- phase D: O = tanh(H2 @ W3^T + b3); F = sum_d O*dX
      // H2 A-fragments quantized to fp8 once; W3 fp8 fed straight to MFMA
      {
        long a8[8];
#pragma unroll
        for (int s = 0; s < 8; ++s) a8[s] = pk_fp8(ldfrag(sm.X, row16, s * 4 + kg));
        float dxr[4];
#pragma unroll
        for (int v = 0; v < 4; ++v) dxr[v] = sm.dx[k & 1][mode][kg * 4 + v][row16];

        for (int jj = 0; jj < 16; jj += 4) {
          PD_ISSUE(rb2, jj + 2)
          PD_PROC(rb0, jj + 0)
          PD_ISSUE(rb3, jj + 3)
          PD_PROC(rb1, jj + 1)
          PD_ISSUE(rb0, jj + 4)
          PD_PROC(rb2, jj + 2)
          PD_ISSUE(rb1, jj + 5)
          PD_PROC(rb3, jj + 3)
        }
      }
      __syncthreads();
    }

    // ---- Heun update + commit prefetched dx for step k+1
    for (int i = tid; i < G * HH; i += NTHR) {
      int r = i >> 7, c = i & (HH - 1);
      sm.Y[r][c] += 0.5f * dt * (sm.K1[r][c] + sm.F[r][c]);
    }
    {
      int which = tid >> 8, rr = (tid >> 4) & 15, d = tid & 15;
      sm.dx[(k + 1) & 1][which][rr][d] = pc2 + 2.0f * ptau * pc1 + 3.0f * ptau * ptau * pc0;
    }
    __syncthreads();
  }

  // ---- classifier + softmax
  if (tid < G * NLBL) {
    int r = tid / NLBL, c = tid % NLBL;
    float s = bl2[c];
    const float* wr = Wl2 + (size_t)c * HH;
#pragma unroll 4
    for (int h = 0; h < HH; ++h) s += sm.Y[r][h] * wr[h];
    sm.logits[tid] = s;
  }
  __syncthreads();
  if (tid < G) {
    float mx = -1e30f;
#pragma unroll
    for (int c = 0; c < NLBL; ++c) mx = fmaxf(mx, sm.logits[tid * NLBL + c]);
    float e[NLBL], sum = 0.f;
#pragma unroll
    for (int c = 0; c < NLBL; ++c) { e[c] = expf(sm.logits[tid * NLBL + c] - mx); sum += e[c]; }
    float inv = 1.0f / sum;
#pragma unroll
    for (int c = 0; c < NLBL; ++c) out[(size_t)(gb + tid) * NLBL + c] = e[c] * inv;
  }
}

extern "C" void kernel_launch(void* const* d_in, const int* in_sizes, int n_in,
                              void* d_out, int out_size, void* d_ws, size_t ws_size,
                              hipStream_t stream) {
  (void)in_sizes; (void)n_in; (void)out_size; (void)ws_size;
  const float* ts = (const float*)d_in[0];
  const float* coeffs = (const float*)d_in[1];
  const float* x0 = (const float*)d_in[2];
  const float* W1 = (const float*)d_in[3];
  const float* b1 = (const float*)d_in[4];
  const float* W2 = (const float*)d_in[5];
  const float* b2 = (const float*)d_in[6];
  const float* W3 = (const float*)d_in[7];
  const float* b3 = (const float*)d_in[8];
  const float* Wl1 = (const float*)d_in[9];
  const float* bl1 = (const float*)d_in[10];
  const float* Wl2 = (const float*)d_in[11];
  const float* bl2 = (const float*)d_in[12];

  char* ws = (char*)d_ws;
  uint2* q8 = (uint2*)ws;                                   // 512 KB fp8 W3 (frag-major)
  float* w3s = (float*)(ws + 524288);                       // 8 KB row scales
  unsigned short* w2b = (unsigned short*)(ws + 532480);     // 128 KB
  unsigned short* w1b = (unsigned short*)(ws + 663552);     // 64 KB

  static_assert(sizeof(SM) <= 160 * 1024, "LDS overflow");
  hipFuncSetAttribute(reinterpret_cast<const void*>(cde_main),
                      hipFuncAttributeMaxDynamicSharedMemorySize, (int)sizeof(SM));

  prep_scale<<<512, 256, 0, stream>>>(W3, w3s);
  prep_pack<<<256, 256, 0, stream>>>(W3, w3s, q8);
  prep_w12<<<256, 256, 0, stream>>>(W1, W2, w1b, w2b);
  cde_main<<<NWG, NTHR, sizeof(SM), stream>>>(ts, coeffs, x0, b1, b2, b3, Wl1, bl1, Wl2, bl2,
                                              w1b, w2b, q8, w3s, (float*)d_out);
}